// Round 2
// baseline (390.525 us; speedup 1.0000x reference)
//
#include <hip/hip_runtime.h>
#include <stdint.h>

#define M_TOT 16384      // B*S = 4*4096
#define K_DIM 2048
#define N_DIM 2048
#define W_ELEMS (N_DIM * K_DIM)   // 4194304

typedef int v4i __attribute__((ext_vector_type(4)));

// ---------------- async global -> LDS, 16B per lane ----------------
__device__ __forceinline__ void async_load16(const void* gptr, void* lptr) {
    __builtin_amdgcn_global_load_lds(
        (__attribute__((address_space(1))) void*)(uintptr_t)gptr,
        (__attribute__((address_space(3))) void*)(uint32_t)(uintptr_t)lptr,
        16, 0, 0);
}

// ---------------- weight sum (for mean), double-accurate ----------------
__global__ void wsum_kernel(const float* __restrict__ w, double* __restrict__ sums) {
    int tid = blockIdx.x * 256 + threadIdx.x;
    const float4* w4 = (const float4*)w;
    double s = 0.0;
    for (int i = tid; i < W_ELEMS / 4; i += 512 * 256) {
        float4 v = w4[i];
        s += (double)v.x + (double)v.y + (double)v.z + (double)v.w;
    }
    #pragma unroll
    for (int off = 32; off; off >>= 1) s += __shfl_down(s, off);
    __shared__ double ls[4];
    if ((threadIdx.x & 63) == 0) ls[threadIdx.x >> 6] = s;
    __syncthreads();
    if (threadIdx.x == 0) atomicAdd(&sums[0], ls[0] + ls[1] + ls[2] + ls[3]);
}

// ---------------- sum |w - mean| ----------------
__global__ void wabs_kernel(const float* __restrict__ w, double* __restrict__ sums) {
    double mean = sums[0] * (1.0 / (double)W_ELEMS);
    int tid = blockIdx.x * 256 + threadIdx.x;
    const float4* w4 = (const float4*)w;
    double s = 0.0;
    for (int i = tid; i < W_ELEMS / 4; i += 512 * 256) {
        float4 v = w4[i];
        s += fabs((double)v.x - mean) + fabs((double)v.y - mean) +
             fabs((double)v.z - mean) + fabs((double)v.w - mean);
    }
    #pragma unroll
    for (int off = 32; off; off >>= 1) s += __shfl_down(s, off);
    __shared__ double ls[4];
    if ((threadIdx.x & 63) == 0) ls[threadIdx.x >> 6] = s;
    __syncthreads();
    if (threadIdx.x == 0) atomicAdd(&sums[1], ls[0] + ls[1] + ls[2] + ls[3]);
}

// ---------------- ternary weight quant -> int8 ----------------
__device__ __forceinline__ int qclamp(float v, int lo, int hi) {
    int q = (int)rintf(v);
    q = q > hi ? hi : (q < lo ? lo : q);
    return q & 255;
}

__global__ void wquant_kernel(const float* __restrict__ w, const double* __restrict__ sums,
                              int8_t* __restrict__ wq) {
    float mean  = (float)(sums[0] * (1.0 / (double)W_ELEMS));
    float scale = (float)fmax(sums[1] * (1.0 / (double)W_ELEMS), 1e-5);
    int i = blockIdx.x * 256 + threadIdx.x;      // one float4 per thread, exact cover
    float4 v = ((const float4*)w)[i];
    int p = qclamp((v.x - mean) / scale, -1, 1)
          | (qclamp((v.y - mean) / scale, -1, 1) << 8)
          | (qclamp((v.z - mean) / scale, -1, 1) << 16)
          | (qclamp((v.w - mean) / scale, -1, 1) << 24);
    ((int*)wq)[i] = p;
}

// ---------------- per-row absmax int8 quant of x ----------------
__global__ void xquant_kernel(const float* __restrict__ x, int8_t* __restrict__ xq,
                              float* __restrict__ xscale) {
    int row = blockIdx.x;
    int t = threadIdx.x;
    const float4* xr = (const float4*)(x + (size_t)row * K_DIM);
    float4 v0 = xr[t];
    float4 v1 = xr[t + 256];
    float m = fmaxf(fmaxf(fmaxf(fabsf(v0.x), fabsf(v0.y)), fmaxf(fabsf(v0.z), fabsf(v0.w))),
                    fmaxf(fmaxf(fabsf(v1.x), fabsf(v1.y)), fmaxf(fabsf(v1.z), fabsf(v1.w))));
    #pragma unroll
    for (int off = 32; off; off >>= 1) m = fmaxf(m, __shfl_down(m, off));
    __shared__ float ls[4];
    if ((t & 63) == 0) ls[t >> 6] = m;
    __syncthreads();
    float scale = fmaxf(fmaxf(fmaxf(ls[0], ls[1]), fmaxf(ls[2], ls[3])), 1e-5f);
    if (t == 0) xscale[row] = scale;
    int* outp = (int*)(xq + (size_t)row * K_DIM);
    float inv = 127.0f / scale;
    int p0 = qclamp(v0.x * inv, -128, 127)
           | (qclamp(v0.y * inv, -128, 127) << 8)
           | (qclamp(v0.z * inv, -128, 127) << 16)
           | (qclamp(v0.w * inv, -128, 127) << 24);
    int p1 = qclamp(v1.x * inv, -128, 127)
           | (qclamp(v1.y * inv, -128, 127) << 8)
           | (qclamp(v1.z * inv, -128, 127) << 16)
           | (qclamp(v1.w * inv, -128, 127) << 24);
    outp[t]       = p0;
    outp[t + 256] = p1;
}

// ---------------- int8 GEMM: C[m,n] = sum_k XQ[m,k]*WQ[n,k], dequant ----------------
// 128(M) x 256(N) block tile, BK=64. 4 waves in 2x2; each wave 64x128 = 4x8
// of 16x16x64 i8 MFMA (acc 128 VGPR). LDS chunk-slot swizzle: chunk c of row r
// stored in slot s = c ^ ((r>>1)&3)  (wave-uniform-base DMA compatible, 0 conflicts).
__global__ __launch_bounds__(256) void gemm_i8_kernel(
    const int8_t* __restrict__ xq, const int8_t* __restrict__ wq,
    const float* __restrict__ xscale, const double* __restrict__ sums,
    float* __restrict__ out)
{
    __shared__ __align__(16) int8_t lsA[128 * 64];   // 8 KB
    __shared__ __align__(16) int8_t lsB[256 * 64];   // 16 KB
    const int tid  = threadIdx.x;
    const int lane = tid & 63;
    const int wv   = tid >> 6;
    const int bn = blockIdx.x, bm = blockIdx.y;

    const int8_t* gA = xq + (size_t)bm * 128 * K_DIM;
    const int8_t* gB = wq + (size_t)bn * 256 * K_DIM;

    // staging: thread covers (row r = tid>>2, slot s = tid&3); r steps by 64
    // keep ((r>>1)&3) invariant (64>>1 = 32, 32&3 = 0)
    const int r = tid >> 2;
    const int s = tid & 3;
    const int c = s ^ ((r >> 1) & 3);            // data chunk stored in slot s
    const size_t gOff0 = (size_t)r * K_DIM + c * 16;

    v4i acc[4][8] = {};

    const int wm = (wv >> 1) * 64;               // 0 / 64
    const int wn = (wv & 1) * 128;               // 0 / 128
    const int fc = lane >> 4;                    // fragment k-chunk (16B)
    const int fr = lane & 15;

    int aoff[4], boff[8];
    #pragma unroll
    for (int i = 0; i < 4; i++) {
        int ra = wm + i * 16 + fr;
        aoff[i] = ra * 64 + (fc ^ ((ra >> 1) & 3)) * 16;
    }
    #pragma unroll
    for (int j = 0; j < 8; j++) {
        int rb = wn + j * 16 + fr;
        boff[j] = rb * 64 + (fc ^ ((rb >> 1) & 3)) * 16;
    }

    for (int k0 = 0; k0 < K_DIM; k0 += 64) {
        __syncthreads();                          // LDS safe to overwrite
        async_load16(gA + gOff0 + k0,                          lsA + tid * 16);
        async_load16(gA + gOff0 + (size_t) 64 * K_DIM + k0,    lsA + 4096  + tid * 16);
        async_load16(gB + gOff0 + k0,                          lsB + tid * 16);
        async_load16(gB + gOff0 + (size_t) 64 * K_DIM + k0,    lsB + 4096  + tid * 16);
        async_load16(gB + gOff0 + (size_t)128 * K_DIM + k0,    lsB + 8192  + tid * 16);
        async_load16(gB + gOff0 + (size_t)192 * K_DIM + k0,    lsB + 12288 + tid * 16);
        __syncthreads();                          // staging complete

        v4i af[4], bf[8];
        #pragma unroll
        for (int i = 0; i < 4; i++) af[i] = *(const v4i*)(lsA + aoff[i]);
        #pragma unroll
        for (int j = 0; j < 8; j++) bf[j] = *(const v4i*)(lsB + boff[j]);

        #pragma unroll
        for (int mi = 0; mi < 4; mi++)
            #pragma unroll
            for (int nj = 0; nj < 8; nj++)
                acc[mi][nj] = __builtin_amdgcn_mfma_i32_16x16x64_i8(
                    af[mi], bf[nj], acc[mi][nj], 0, 0, 0);
    }

    // epilogue: dequant. C/D layout: col = lane&15, row = (lane>>4)*4 + reg
    float wscale = (float)fmax(sums[1] * (1.0 / (double)W_ELEMS), 1e-5);
    float f127 = wscale * (1.0f / 127.0f);
    #pragma unroll
    for (int mi = 0; mi < 4; mi++) {
        #pragma unroll
        for (int rg = 0; rg < 4; rg++) {
            int mg = bm * 128 + wm + mi * 16 + (lane >> 4) * 4 + rg;
            float fs = f127 * xscale[mg];
            float* orow = out + (size_t)mg * N_DIM + bn * 256 + wn;
            #pragma unroll
            for (int nj = 0; nj < 8; nj++)
                orow[nj * 16 + fr] = fs * (float)acc[mi][nj][rg];
        }
    }
}

extern "C" void kernel_launch(void* const* d_in, const int* in_sizes, int n_in,
                              void* d_out, int out_size, void* d_ws, size_t ws_size,
                              hipStream_t stream) {
    const float* x = (const float*)d_in[0];
    const float* w = (const float*)d_in[1];
    float* out = (float*)d_out;

    char* ws = (char*)d_ws;
    double* sums   = (double*)ws;                               // 16 B
    float*  xscale = (float*)(ws + 64);                         // 64 KB
    int8_t* xq     = (int8_t*)(ws + 64 + 65536);                // 32 MB
    int8_t* wq     = (int8_t*)(ws + 64 + 65536 + (size_t)M_TOT * K_DIM); // 4 MB

    hipMemsetAsync(sums, 0, 16, stream);
    wsum_kernel <<<512, 256, 0, stream>>>(w, sums);
    wabs_kernel <<<512, 256, 0, stream>>>(w, sums);
    wquant_kernel<<<W_ELEMS / 1024, 256, 0, stream>>>(w, sums, wq);
    xquant_kernel<<<M_TOT, 256, 0, stream>>>(x, xq, xscale);
    gemm_i8_kernel<<<dim3(N_DIM / 256, M_TOT / 128), 256, 0, stream>>>(xq, wq, xscale, sums, out);
}

// Round 3
// 336.621 us; speedup vs baseline: 1.1601x; 1.1601x over previous
//
#include <hip/hip_runtime.h>
#include <stdint.h>

#define M_TOT 16384      // B*S = 4*4096
#define K_DIM 2048
#define N_DIM 2048
#define W_ELEMS (N_DIM * K_DIM)   // 4194304

typedef int v4i __attribute__((ext_vector_type(4)));

// ---------------- async global -> LDS, 16B per lane ----------------
__device__ __forceinline__ void async_load16(const void* gptr, void* lptr) {
    __builtin_amdgcn_global_load_lds(
        (__attribute__((address_space(1))) void*)(uintptr_t)gptr,
        (__attribute__((address_space(3))) void*)(uint32_t)(uintptr_t)lptr,
        16, 0, 0);
}

// ---------------- weight sum (for mean), double-accurate ----------------
__global__ void wsum_kernel(const float* __restrict__ w, double* __restrict__ sums) {
    int tid = blockIdx.x * 256 + threadIdx.x;
    const float4* w4 = (const float4*)w;
    double s = 0.0;
    for (int i = tid; i < W_ELEMS / 4; i += 512 * 256) {
        float4 v = w4[i];
        s += (double)v.x + (double)v.y + (double)v.z + (double)v.w;
    }
    #pragma unroll
    for (int off = 32; off; off >>= 1) s += __shfl_down(s, off);
    __shared__ double ls[4];
    if ((threadIdx.x & 63) == 0) ls[threadIdx.x >> 6] = s;
    __syncthreads();
    if (threadIdx.x == 0) atomicAdd(&sums[0], ls[0] + ls[1] + ls[2] + ls[3]);
}

// ---------------- sum |w - mean| ----------------
__global__ void wabs_kernel(const float* __restrict__ w, double* __restrict__ sums) {
    double mean = sums[0] * (1.0 / (double)W_ELEMS);
    int tid = blockIdx.x * 256 + threadIdx.x;
    const float4* w4 = (const float4*)w;
    double s = 0.0;
    for (int i = tid; i < W_ELEMS / 4; i += 512 * 256) {
        float4 v = w4[i];
        s += fabs((double)v.x - mean) + fabs((double)v.y - mean) +
             fabs((double)v.z - mean) + fabs((double)v.w - mean);
    }
    #pragma unroll
    for (int off = 32; off; off >>= 1) s += __shfl_down(s, off);
    __shared__ double ls[4];
    if ((threadIdx.x & 63) == 0) ls[threadIdx.x >> 6] = s;
    __syncthreads();
    if (threadIdx.x == 0) atomicAdd(&sums[1], ls[0] + ls[1] + ls[2] + ls[3]);
}

// ---------------- ternary weight quant -> int8 ----------------
__device__ __forceinline__ int qclamp(float v, int lo, int hi) {
    int q = (int)rintf(v);
    q = q > hi ? hi : (q < lo ? lo : q);
    return q & 255;
}

__global__ void wquant_kernel(const float* __restrict__ w, const double* __restrict__ sums,
                              int8_t* __restrict__ wq) {
    float mean  = (float)(sums[0] * (1.0 / (double)W_ELEMS));
    float scale = (float)fmax(sums[1] * (1.0 / (double)W_ELEMS), 1e-5);
    int i = blockIdx.x * 256 + threadIdx.x;      // one float4 per thread, exact cover
    float4 v = ((const float4*)w)[i];
    int p = qclamp((v.x - mean) / scale, -1, 1)
          | (qclamp((v.y - mean) / scale, -1, 1) << 8)
          | (qclamp((v.z - mean) / scale, -1, 1) << 16)
          | (qclamp((v.w - mean) / scale, -1, 1) << 24);
    ((int*)wq)[i] = p;
}

// ---------------- per-row absmax int8 quant of x ----------------
__global__ void xquant_kernel(const float* __restrict__ x, int8_t* __restrict__ xq,
                              float* __restrict__ xscale) {
    int row = blockIdx.x;
    int t = threadIdx.x;
    const float4* xr = (const float4*)(x + (size_t)row * K_DIM);
    float4 v0 = xr[t];
    float4 v1 = xr[t + 256];
    float m = fmaxf(fmaxf(fmaxf(fabsf(v0.x), fabsf(v0.y)), fmaxf(fabsf(v0.z), fabsf(v0.w))),
                    fmaxf(fmaxf(fabsf(v1.x), fabsf(v1.y)), fmaxf(fabsf(v1.z), fabsf(v1.w))));
    #pragma unroll
    for (int off = 32; off; off >>= 1) m = fmaxf(m, __shfl_down(m, off));
    __shared__ float ls[4];
    if ((t & 63) == 0) ls[t >> 6] = m;
    __syncthreads();
    float scale = fmaxf(fmaxf(fmaxf(ls[0], ls[1]), fmaxf(ls[2], ls[3])), 1e-5f);
    if (t == 0) xscale[row] = scale;
    int* outp = (int*)(xq + (size_t)row * K_DIM);
    int p0 = qclamp(v0.x / scale * 127.0f, -128, 127)
           | (qclamp(v0.y / scale * 127.0f, -128, 127) << 8)
           | (qclamp(v0.z / scale * 127.0f, -128, 127) << 16)
           | (qclamp(v0.w / scale * 127.0f, -128, 127) << 24);
    int p1 = qclamp(v1.x / scale * 127.0f, -128, 127)
           | (qclamp(v1.y / scale * 127.0f, -128, 127) << 8)
           | (qclamp(v1.z / scale * 127.0f, -128, 127) << 16)
           | (qclamp(v1.w / scale * 127.0f, -128, 127) << 24);
    outp[t]       = p0;
    outp[t + 256] = p1;
}

// ---------------- int8 GEMM: C[m,n] = sum_k XQ[m,k]*WQ[n,k], dequant ----------------
// 128x128 block tile, BK=64, 4 waves each 64x64 (4x4 of 16x16x64 MFMA, 64 AGPR).
// Double-buffered LDS with ONE barrier/iter: issue DMA for tile t+1 right after
// the barrier, compute tile t; the compiler's mandatory vmcnt(0) before the NEXT
// s_barrier drains it — DMA latency hidden behind the whole compute window.
// LDS chunk-slot swizzle: chunk c of row r stored in slot s = c ^ ((r>>1)&3).
__global__ __launch_bounds__(256) void gemm_i8_kernel(
    const int8_t* __restrict__ xq, const int8_t* __restrict__ wq,
    const float* __restrict__ xscale, const double* __restrict__ sums,
    float* __restrict__ out)
{
    __shared__ __align__(16) int8_t lsA[2][128 * 64];   // 2 x 8 KB
    __shared__ __align__(16) int8_t lsB[2][128 * 64];   // 2 x 8 KB
    const int tid  = threadIdx.x;
    const int lane = tid & 63;
    const int wv   = tid >> 6;
    const int bn = blockIdx.x, bm = blockIdx.y;

    const int8_t* gA = xq + (size_t)bm * 128 * K_DIM;
    const int8_t* gB = wq + (size_t)bn * 128 * K_DIM;

    // staging: thread covers (row r = tid>>2, slot s = tid&3)
    const int r = tid >> 2;
    const int s = tid & 3;
    const int c = s ^ ((r >> 1) & 3);            // data chunk stored in slot s
    const size_t gOff0 = (size_t)r * K_DIM + c * 16;
    const size_t gOff1 = gOff0 + (size_t)64 * K_DIM;   // r+64: same xor ((64>>1)&3==0)

    v4i acc[4][4] = {};

    const int wm = (wv >> 1) * 64;
    const int wn = (wv & 1) * 64;
    const int fc = lane >> 4;                    // fragment k-chunk (16B)
    const int fr = lane & 15;

    int aoff[4], boff[4];
    #pragma unroll
    for (int i = 0; i < 4; i++) {
        int ra = wm + i * 16 + fr;
        aoff[i] = ra * 64 + (fc ^ ((ra >> 1) & 3)) * 16;
        int rb = wn + i * 16 + fr;
        boff[i] = rb * 64 + (fc ^ ((rb >> 1) & 3)) * 16;
    }

    #define STAGE(buf, k0)                                            \
        do {                                                          \
            async_load16(gA + gOff0 + (k0), lsA[buf] + tid * 16);     \
            async_load16(gA + gOff1 + (k0), lsA[buf] + 4096 + tid * 16); \
            async_load16(gB + gOff0 + (k0), lsB[buf] + tid * 16);     \
            async_load16(gB + gOff1 + (k0), lsB[buf] + 4096 + tid * 16); \
        } while (0)

    #define COMPUTE(buf)                                              \
        do {                                                          \
            v4i af[4], bf[4];                                         \
            _Pragma("unroll")                                         \
            for (int i = 0; i < 4; i++) af[i] = *(const v4i*)(lsA[buf] + aoff[i]); \
            _Pragma("unroll")                                         \
            for (int i = 0; i < 4; i++) bf[i] = *(const v4i*)(lsB[buf] + boff[i]); \
            _Pragma("unroll")                                         \
            for (int mi = 0; mi < 4; mi++)                            \
                _Pragma("unroll")                                     \
                for (int nj = 0; nj < 4; nj++)                        \
                    acc[mi][nj] = __builtin_amdgcn_mfma_i32_16x16x64_i8( \
                        af[mi], bf[nj], acc[mi][nj], 0, 0, 0);        \
        } while (0)

    STAGE(0, 0);                                  // prologue: tile 0 -> buf 0
    for (int k0 = 0; k0 < K_DIM; k0 += 128) {
        __syncthreads();                          // drains vmcnt: tile(k0) in buf0 ready
        if (k0 + 64 < K_DIM) STAGE(1, k0 + 64);   // prefetch next into buf1
        COMPUTE(0);
        __syncthreads();                          // drains: tile(k0+64) in buf1 ready
        if (k0 + 128 < K_DIM) STAGE(0, k0 + 128); // prefetch into buf0
        COMPUTE(1);
    }
    #undef STAGE
    #undef COMPUTE

    // epilogue: dequant. C/D layout: col = lane&15, row = (lane>>4)*4 + reg
    float wscale = (float)fmax(sums[1] * (1.0 / (double)W_ELEMS), 1e-5);
    float f127 = wscale * (1.0f / 127.0f);
    #pragma unroll
    for (int mi = 0; mi < 4; mi++) {
        #pragma unroll
        for (int rg = 0; rg < 4; rg++) {
            int mg = bm * 128 + wm + mi * 16 + (lane >> 4) * 4 + rg;
            float fs = f127 * xscale[mg];
            float* orow = out + (size_t)mg * N_DIM + bn * 128 + wn;
            #pragma unroll
            for (int nj = 0; nj < 4; nj++)
                orow[nj * 16 + fr] = fs * (float)acc[mi][nj][rg];
        }
    }
}

extern "C" void kernel_launch(void* const* d_in, const int* in_sizes, int n_in,
                              void* d_out, int out_size, void* d_ws, size_t ws_size,
                              hipStream_t stream) {
    const float* x = (const float*)d_in[0];
    const float* w = (const float*)d_in[1];
    float* out = (float*)d_out;

    char* ws = (char*)d_ws;
    double* sums   = (double*)ws;                               // 16 B
    float*  xscale = (float*)(ws + 64);                         // 64 KB
    int8_t* xq     = (int8_t*)(ws + 64 + 65536);                // 32 MB
    int8_t* wq     = (int8_t*)(ws + 64 + 65536 + (size_t)M_TOT * K_DIM); // 4 MB

    hipMemsetAsync(sums, 0, 16, stream);
    wsum_kernel <<<512, 256, 0, stream>>>(w, sums);
    wabs_kernel <<<512, 256, 0, stream>>>(w, sums);
    wquant_kernel<<<W_ELEMS / 1024, 256, 0, stream>>>(w, sums, wq);
    xquant_kernel<<<M_TOT, 256, 0, stream>>>(x, xq, xscale);
    gemm_i8_kernel<<<dim3(N_DIM / 128, M_TOT / 128), 256, 0, stream>>>(xq, wq, xscale, sums, out);
}